// Round 11
// baseline (577.779 us; speedup 1.0000x reference)
//
#include <hip/hip_runtime.h>
#include <math.h>

#define B_ 4
#define S_ 2048
#define D_ 768
#define H_ 12
#define DH_ 64
#define FF_ 3072
#define LDQ (3*D_)

using short8  = __attribute__((ext_vector_type(8))) short;
using f32x4   = __attribute__((ext_vector_type(4))) float;
using f32x16  = __attribute__((ext_vector_type(16))) float;
using float4v = __attribute__((ext_vector_type(4))) float;
using ushort4v= __attribute__((ext_vector_type(4))) unsigned short;

__device__ __forceinline__ unsigned short f2bf(float f) {
  unsigned u = __builtin_bit_cast(unsigned, f);
  u += 0x7FFFu + ((u >> 16) & 1u);   // round-to-nearest-even
  return (unsigned short)(u >> 16);
}

__device__ __forceinline__ unsigned cvt_pk_bf16(float a, float b) {
  unsigned r;
  asm("v_cvt_pk_bf16_f32 %0, %1, %2" : "=v"(r) : "v"(a), "v"(b));
  return r;   // lo = bf16(a), hi = bf16(b)
}

// tanh-form GELU: 0.5x(1+tanh(0.79788456(x+0.044715x^3))), max abs err ~3e-4.
__device__ __forceinline__ float gelu_tanh(float x) {
  float x2 = x * x;
  float y  = x * fmaf(0.0356774081f, x2, 0.7978845608f);
  float e  = exp2f(y * 2.885390082f);     // e^(2y)
  float t  = 1.0f - 2.0f / (e + 1.0f);
  float hx = 0.5f * x;
  return fmaf(hx, t, hx);
}

__device__ __forceinline__ void gload16(const void* g, void* l) {
  __builtin_amdgcn_global_load_lds(
      (const __attribute__((address_space(1))) unsigned*)g,
      (__attribute__((address_space(3))) unsigned*)l, 16, 0, 0);
}

// ---------------- fused weight transpose + cast (all 6 weights, one launch) ----------------
// in [K][N] f32 -> out [N][K] bf16
__global__ __launch_bounds__(256) void transpose_cast_multi_kernel(
    const float* __restrict__ Wq, const float* __restrict__ Wk,
    const float* __restrict__ Wv, const float* __restrict__ Wo,
    const float* __restrict__ W1, const float* __restrict__ W2,
    unsigned short* __restrict__ WqT, unsigned short* __restrict__ WkT,
    unsigned short* __restrict__ WvT, unsigned short* __restrict__ WoT,
    unsigned short* __restrict__ W1T, unsigned short* __restrict__ W2T) {
  __shared__ float tile[32][33];
  int bid = blockIdx.x;
  const float* in; unsigned short* out; int K, N, t;
  if (bid < 2304) {                 // Wq/Wk/Wv/Wo: 576 tiles each, 768x768
    int seg = bid / 576; t = bid % 576; K = D_; N = D_;
    in  = seg == 0 ? Wq  : seg == 1 ? Wk  : seg == 2 ? Wv  : Wo;
    out = seg == 0 ? WqT : seg == 1 ? WkT : seg == 2 ? WvT : WoT;
  } else if (bid < 4608) {          // W1: 768x3072
    t = bid - 2304; K = D_; N = FF_; in = W1; out = W1T;
  } else {                          // W2: 3072x768
    t = bid - 4608; K = FF_; N = D_; in = W2; out = W2T;
  }
  int ntk = K / 32;
  int k0 = (t % ntk) * 32, n0 = (t / ntk) * 32;
  int tx = threadIdx.x, ty = threadIdx.y;
#pragma unroll
  for (int i = 0; i < 4; i++)
    tile[ty + 8*i][tx] = in[(size_t)(k0 + ty + 8*i) * N + n0 + tx];
  __syncthreads();
#pragma unroll
  for (int i = 0; i < 4; i++)
    out[(size_t)(n0 + ty + 8*i) * K + k0 + tx] = f2bf(tile[tx][ty + 8*i]);
}

// ---------------- bias concat: [bq | bk | bv] -> 2304 floats ----------------
__global__ void bias_cat_kernel(const float* __restrict__ bq, const float* __restrict__ bk,
                                const float* __restrict__ bv, float* __restrict__ dst) {
  int i = blockIdx.x * 256 + threadIdx.x;
  if (i >= 3 * D_) return;
  float v;
  if (i < D_)            v = bq[i];
  else if (i < 2 * D_)   v = bk[i - D_];
  else                   v = bv[i - 2 * D_];
  dst[i] = v;
}

// ---------------- LayerNorm: fp32 in -> bf16 out, one wave per row of 768 ----------------
__global__ __launch_bounds__(256) void layernorm_kernel(
    const float* __restrict__ x, const float* __restrict__ g,
    const float* __restrict__ b, unsigned short* __restrict__ out) {
  int wave = threadIdx.x >> 6, lane = threadIdx.x & 63;
  int row = blockIdx.x * 4 + wave;
  const float* xr = x + (size_t)row * D_;
  float4v v[3];
  float sum = 0.f, sq = 0.f;
#pragma unroll
  for (int i = 0; i < 3; i++) {
    v[i] = reinterpret_cast<const float4v*>(xr)[lane + 64*i];
#pragma unroll
    for (int j = 0; j < 4; j++) { sum += v[i][j]; sq += v[i][j]*v[i][j]; }
  }
#pragma unroll
  for (int d = 1; d < 64; d <<= 1) { sum += __shfl_xor(sum, d); sq += __shfl_xor(sq, d); }
  float mu   = sum * (1.0f / D_);
  float var  = sq  * (1.0f / D_) - mu * mu;
  float rstd = rsqrtf(var + 1e-5f);
  unsigned short* orow = out + (size_t)row * D_;
#pragma unroll
  for (int i = 0; i < 3; i++) {
    int idx = (lane + 64*i) * 4;
    ushort4v o;
#pragma unroll
    for (int j = 0; j < 4; j++)
      o[j] = f2bf((v[i][j] - mu) * rstd * g[idx + j] + b[idx + j]);
    *reinterpret_cast<ushort4v*>(orow + idx) = o;
  }
}

// ---------------- bf16 MFMA GEMM v5: 2-slot ring, 32KB LDS, 5 blocks/CU ----------------
// 128x128 tile, BK=32, 4 waves. Unified A|B LDS row (128B, 8x16B slots, ^(row&7)
// swizzle -> measured-zero conflicts). T3-minimum schedule: STAGE(next) issued
// right after the barrier (its slot was drained by that barrier), one
// vmcnt(0)+barrier per chunk at the END; staged loads fly across the whole
// compute phase. 32KB LDS -> 5 blocks/CU (20 waves/CU): cross-block wave overlap
// absorbs the barrier skew that capped v3 at MfmaUtil 22%.
#define EPI_QKV   0
#define EPI_OPROJ 1
#define EPI_GELU  2
#define EPI_FINAL 3

template<int EPI>
__global__ __launch_bounds__(256, 5) void gemm_kernel(
    const unsigned short* __restrict__ A, int lda,
    const unsigned short* __restrict__ BT, int K,
    const float* __restrict__ bias,
    const float* __restrict__ resid,
    float* __restrict__ outf,
    unsigned short* __restrict__ outh,
    int ldo, float ascale, int nN) {
  __shared__ __attribute__((aligned(16))) unsigned short Ls[2][128*64];
  int tid = threadIdx.x;
  int wave = tid >> 6, lane = tid & 63;
  int lrow = lane & 15, lk = lane >> 4;      // lk = k-slot 0..3 (8 elems each)
  int bid = blockIdx.x;
  int xcd = bid & 7, j = bid >> 3;
  int nM8 = gridDim.x / (8 * nN);            // = 8 (64 M-panels / 8 XCDs)
  int m0 = (xcd * nM8 + j / nN) * 128;
  int n0 = (j % nN) * 128;
  int wm = (wave >> 1) * 64, wn = (wave & 1) * 64;

  // Unified staging: LDS row r = [A[m0+r] slots 0..3 | B[n0+r] slots 4..7],
  // slot s8 holds content m = s8 ^ (r&7). Source pre-swizzled per-lane (rule #21).
  // Per-thread source base is loop-invariant: precompute, add k0 per chunk.
  const unsigned short* srcBase[4];
  int ldsDst[4];
#pragma unroll
  for (int i = 0; i < 4; i++) {
    int ch = i * 256 + tid;
    int row = ch >> 3, s8 = ch & 7;
    int m = s8 ^ (row & 7);
    srcBase[i] = (m < 4)
      ? A  + (size_t)(m0 + row) * lda + m * 8
      : BT + (size_t)(n0 + row) * K   + (m - 4) * 8;
    ldsDst[i] = (i*256 + wave*64) * 8;
  }
  auto STAGE = [&](int buf, int k0) {
#pragma unroll
    for (int i = 0; i < 4; i++)
      gload16(srcBase[i] + k0, &Ls[buf][ldsDst[i]]);
  };

  // fragment read offsets (loop-invariant)
  int offA[4], offB[4];
#pragma unroll
  for (int mi = 0; mi < 4; mi++) {
    int row = wm + mi*16 + lrow;
    offA[mi] = row*64 + ((lk ^ (row & 7)) * 8);
  }
#pragma unroll
  for (int ni = 0; ni < 4; ni++) {
    int row = wn + ni*16 + lrow;
    offB[ni] = row*64 + (((4 + lk) ^ (row & 7)) * 8);
  }

  f32x4 acc[4][4] = {};
  int nt = K / 32;
  STAGE(0, 0);
  asm volatile("s_waitcnt vmcnt(0)" ::: "memory");
  __builtin_amdgcn_s_barrier();
  for (int t = 0; t < nt; t++) {
    int cur = t & 1;
    if (t + 1 < nt) STAGE(cur ^ 1, (t + 1) * 32);  // slot cur^1 drained by last barrier
    const unsigned short* Lc = Ls[cur];
    short8 af[4], bf[4];
#pragma unroll
    for (int mi = 0; mi < 4; mi++)
      af[mi] = *reinterpret_cast<const short8*>(&Lc[offA[mi]]);
#pragma unroll
    for (int ni = 0; ni < 4; ni++)
      bf[ni] = *reinterpret_cast<const short8*>(&Lc[offB[ni]]);
    __builtin_amdgcn_s_setprio(1);
#pragma unroll
    for (int mi = 0; mi < 4; mi++)
#pragma unroll
      for (int ni = 0; ni < 4; ni++)
        acc[mi][ni] = __builtin_amdgcn_mfma_f32_16x16x32_bf16(af[mi], bf[ni], acc[mi][ni], 0, 0, 0);
    __builtin_amdgcn_s_setprio(0);
    asm volatile("s_waitcnt vmcnt(0)" ::: "memory");  // next tile landed (flew over MFMA)
    __builtin_amdgcn_s_barrier();
  }
#pragma unroll
  for (int mi = 0; mi < 4; mi++) {
#pragma unroll
    for (int ni = 0; ni < 4; ni++) {
#pragma unroll
      for (int r = 0; r < 4; r++) {
        int gm = m0 + wm + mi*16 + (lane >> 4)*4 + r;
        int gn = n0 + wn + ni*16 + lrow;
        float v = acc[mi][ni][r] + bias[gn];
        if constexpr (EPI == EPI_QKV) {
          if (gn < D_) v *= ascale;   // Q pre-scale: 1/sqrt(DH)*log2(e)
          float nb = __shfl_xor(v, 1);
          if (!(lane & 1))
            *reinterpret_cast<unsigned*>(&outh[(size_t)gm * ldo + gn]) = cvt_pk_bf16(v, nb);
        } else if constexpr (EPI == EPI_OPROJ) {
          size_t idx = (size_t)gm * ldo + gn;
          outf[idx] = v + resid[idx];
        } else if constexpr (EPI == EPI_GELU) {
          float gv = gelu_tanh(v);
          float nb = __shfl_xor(gv, 1);
          if (!(lane & 1))
            *reinterpret_cast<unsigned*>(&outh[(size_t)gm * ldo + gn]) = cvt_pk_bf16(gv, nb);
        } else {  // EPI_FINAL
          size_t idx = (size_t)gm * ldo + gn;
          outf[idx] = v + resid[idx];
        }
      }
    }
  }
}

// ---------------- causal flash attention v7 (unchanged from round 8) ----------------
__global__ __launch_bounds__(256, 3) void attn_kernel(
    const unsigned short* __restrict__ qkv,
    unsigned short* __restrict__ o) {
  __shared__ __attribute__((aligned(16))) unsigned short Ks[2][64*64];  // [key][dh] swizzled
  __shared__ __attribute__((aligned(16))) unsigned short VT[2][64*64];  // [dh][key] swizzled
  int tid = threadIdx.x;
  int wave = tid >> 6, lane = tid & 63;
  int ql = lane & 31, hi = lane >> 5;
  int bid = blockIdx.x;
  int xcd = bid & 7, r = bid >> 3;           // r in [0,96)
  int bh = xcd * 6 + (r % 6);                // 0..47, fixed per XCD
  int qtile = 15 - (r / 6);                  // heavy (15) first
  int bb = bh / H_, hh = bh % H_;
  const unsigned short* qb = qkv + (size_t)bb * S_ * LDQ + hh * DH_;
  const unsigned short* kb = qb + D_;
  const unsigned short* vb = qb + 2 * D_;

  int sr = tid >> 2;                 // K row 0..63
  int sc16 = (tid & 3) * 16;         // K col (elems)
  int kp = tid & 31, dh0 = (tid >> 5) * 8;
  uint4 krA, krB, vrA, vrB;

  auto LOADR = [&](int kb0) {
    const unsigned short* ksrc = kb + (size_t)(kb0 + sr) * LDQ + sc16;
    krA = *reinterpret_cast<const uint4*>(ksrc);
    krB = *reinterpret_cast<const uint4*>(ksrc + 8);
    const unsigned short* vsrc = vb + (size_t)(kb0 + 2*kp) * LDQ + dh0;
    vrA = *reinterpret_cast<const uint4*>(vsrc);
    vrB = *reinterpret_cast<const uint4*>(vsrc + LDQ);
  };
  auto WRITE = [&](int buf) {
    int sw = (sr & 7) << 4;
    int cb = sc16 * 2;
    *reinterpret_cast<uint4*>(&Ks[buf][(sr*128 + (cb ^ sw)) >> 1]) = krA;
    *reinterpret_cast<uint4*>(&Ks[buf][(sr*128 + ((cb + 16) ^ sw)) >> 1]) = krB;
    union { uint4 u4; unsigned short s[8]; } a, b;
    a.u4 = vrA; b.u4 = vrB;
#pragma unroll
    for (int j2 = 0; j2 < 8; j2++) {
      int row = dh0 + j2, sw2 = (row & 7) << 4;
      *reinterpret_cast<unsigned*>(&VT[buf][(row*128 + ((4*kp) ^ sw2)) >> 1]) =
          (unsigned)a.s[j2] | ((unsigned)b.s[j2] << 16);
    }
  };

  int q0 = qtile * 128;
  int qw = q0 + wave * 32;
  int myq = qw + ql;

  short8 qf[4];
#pragma unroll
  for (int dblk = 0; dblk < 4; dblk++)
    qf[dblk] = *reinterpret_cast<const short8*>(qb + (size_t)myq * LDQ + dblk*16 + hi*8);

  f32x16 oaccT[2] = {};
  float mst = -1e30f, lst = 0.f;
  int nt = q0 / 64 + 2;   // always even

  auto TILE = [&](int kt, int cur) {
    int kb0 = kt * 64;
    bool has_next = (kt + 1 < nt);
    if (has_next) LOADR((kt + 1) * 64);   // early issue

    if (kb0 <= qw + 31) {
      f32x16 sc[2] = {};
      __builtin_amdgcn_s_setprio(1);
#pragma unroll
      for (int dblk = 0; dblk < 4; dblk++) {
#pragma unroll
        for (int blk = 0; blk < 2; blk++) {
          int row = blk*32 + ql;
          int sw = (row & 7) << 4;
          short8 kf = *reinterpret_cast<const short8*>(
              &Ks[cur][(row*128 + (((unsigned)(dblk*32 + hi*16)) ^ sw)) >> 1]);
          sc[blk] = __builtin_amdgcn_mfma_f32_32x32x16_bf16(kf, qf[dblk], sc[blk], 0, 0, 0);
        }
      }
      __builtin_amdgcn_s_setprio(0);
      bool full = (kb0 + 63 <= qw);
      if (!full) {
#pragma unroll
        for (int blk = 0; blk < 2; blk++)
#pragma unroll
          for (int r2 = 0; r2 < 16; r2++) {
            int key = kb0 + blk*32 + (r2 & 3) + 8*(r2 >> 2) + 4*hi;
            if (key > myq) sc[blk][r2] = -1e30f;
          }
      }
      float pm0 = -1e30f, pm1 = -1e30f, pm2 = -1e30f, pm3 = -1e30f;
#pragma unroll
      for (int blk = 0; blk < 2; blk++)
#pragma unroll
        for (int g = 0; g < 4; g++) {
          pm0 = fmaxf(pm0, sc[blk][4*g]);
          pm1 = fmaxf(pm1, sc[blk][4*g+1]);
          pm2 = fmaxf(pm2, sc[blk][4*g+2]);
          pm3 = fmaxf(pm3, sc[blk][4*g+3]);
        }
      float mx = fmaxf(fmaxf(pm0, pm1), fmaxf(pm2, pm3));
      mx = fmaxf(mx, __shfl_xor(mx, 32));
      if (!__all(mx <= mst + 8.0f)) {
        float mnew = fmaxf(mst, mx);
        float fac = exp2f(mst - mnew);
        lst *= fac;
#pragma unroll
        for (int db = 0; db < 2; db++)
#pragma unroll
          for (int r2 = 0; r2 < 16; r2++) oaccT[db][r2] *= fac;
        mst = mnew;
      }
      short8 pa[4];
      float rs = 0.f;
#pragma unroll
      for (int b = 0; b < 2; b++) {
#pragma unroll
        for (int so = 0; so < 2; so++) {
          float p0 = exp2f(sc[b][8*so + 0] - mst);
          float p1 = exp2f(sc[b][8*so + 1] - mst);
          float p2 = exp2f(sc[b][8*so + 2] - mst);
          float p3 = exp2f(sc[b][8*so + 3] - mst);
          float p4 = exp2f(sc[b][8*so + 4] - mst);
          float p5 = exp2f(sc[b][8*so + 5] - mst);
          float p6 = exp2f(sc[b][8*so + 6] - mst);
          float p7 = exp2f(sc[b][8*so + 7] - mst);
          rs += ((p0 + p1) + (p2 + p3)) + ((p4 + p5) + (p6 + p7));
          unsigned W0 = cvt_pk_bf16(p0, p1);
          unsigned W1 = cvt_pk_bf16(p2, p3);
          unsigned W2 = cvt_pk_bf16(p4, p5);
          unsigned W3 = cvt_pk_bf16(p6, p7);
          asm volatile("v_permlane32_swap_b32 %0, %1" : "+v"(W0), "+v"(W2));
          asm volatile("v_permlane32_swap_b32 %0, %1" : "+v"(W1), "+v"(W3));
          union { uint4 u; short8 s; } cvtu;
          cvtu.u.x = W0; cvtu.u.y = W1; cvtu.u.z = W2; cvtu.u.w = W3;
          pa[2*b + so] = cvtu.s;
        }
      }
      rs += __shfl_xor(rs, 32);
      lst += rs;
      __builtin_amdgcn_s_setprio(1);
#pragma unroll
      for (int ks = 0; ks < 4; ks++) {
        int cb = ks*32 + hi*16;
#pragma unroll
        for (int db = 0; db < 2; db++) {
          int row = db*32 + ql;
          int sw = (row & 7) << 4;
          short8 vf = *reinterpret_cast<const short8*>(&VT[cur][(row*128 + (cb ^ sw)) >> 1]);
          oaccT[db] = __builtin_amdgcn_mfma_f32_32x32x16_bf16(vf, pa[ks], oaccT[db], 0, 0, 0);
        }
      }
      __builtin_amdgcn_s_setprio(0);
    }

    if (has_next) WRITE(cur ^ 1);
    __syncthreads();
  };

  LOADR(0);
  WRITE(0);
  __syncthreads();
  for (int kt = 0; kt < nt; kt += 2) {
    TILE(kt, 0);
    TILE(kt + 1, 1);
  }

  float inv = 1.0f / lst;
  unsigned short* ob = o + ((size_t)(bb * S_ + myq)) * D_ + hh * DH_;
#pragma unroll
  for (int db = 0; db < 2; db++)
#pragma unroll
    for (int g = 0; g < 8; g++) {
      int r2 = 2 * g;
      int dh = db*32 + (r2 & 3) + 8*(r2 >> 2) + 4*hi;
      unsigned pk = cvt_pk_bf16(oaccT[db][r2] * inv, oaccT[db][r2+1] * inv);
      *reinterpret_cast<unsigned*>(ob + dh) = pk;
    }
}

extern "C" void kernel_launch(void* const* d_in, const int* in_sizes, int n_in,
                              void* d_out, int out_size, void* d_ws, size_t ws_size,
                              hipStream_t stream) {
  (void)in_sizes; (void)n_in; (void)out_size; (void)ws_size;
  const float* x    = (const float*)d_in[0];
  const float* ln1g = (const float*)d_in[1];
  const float* ln1b = (const float*)d_in[2];
  const float* Wq   = (const float*)d_in[3];
  const float* bq   = (const float*)d_in[4];
  const float* Wk   = (const float*)d_in[5];
  const float* bk   = (const float*)d_in[6];
  const float* Wv   = (const float*)d_in[7];
  const float* bv   = (const float*)d_in[8];
  const float* Wo   = (const float*)d_in[9];
  const float* bo   = (const float*)d_in[10];
  const float* ln2g = (const float*)d_in[11];
  const float* ln2b = (const float*)d_in[12];
  const float* W1   = (const float*)d_in[13];
  const float* b1   = (const float*)d_in[14];
  const float* W2   = (const float*)d_in[15];
  const float* b2   = (const float*)d_in[16];
  float* out = (float*)d_out;

  char* ws = (char*)d_ws;
  size_t off = 0;
  auto alloc = [&](size_t bytes) {
    char* p = ws + off;
    off += (bytes + 255) & ~(size_t)255;
    return p;
  };
  unsigned short* WqT = (unsigned short*)alloc((size_t)D_*D_*2);
  unsigned short* WkT = (unsigned short*)alloc((size_t)D_*D_*2);
  unsigned short* WvT = (unsigned short*)alloc((size_t)D_*D_*2);
  unsigned short* WoT = (unsigned short*)alloc((size_t)D_*D_*2);
  unsigned short* W1T = (unsigned short*)alloc((size_t)D_*FF_*2);
  unsigned short* W2T = (unsigned short*)alloc((size_t)FF_*D_*2);
  unsigned short* h   = (unsigned short*)alloc((size_t)B_*S_*D_*2);
  unsigned short* qkv = (unsigned short*)alloc((size_t)B_*S_*LDQ*2);  // [8192][2304]
  unsigned short* ob  = (unsigned short*)alloc((size_t)B_*S_*D_*2);   // [8192][768]
  float* bias_cat     = (float*)alloc((size_t)3*D_*4);
  unsigned short* ffb = qkv;  // reuse qkv+ob span (50.3MB = B*S*FF*2)
  unsigned short* h2  = h;    // reuse h

  const float qscale = 0.125f * 1.4426950408889634f;  // 1/sqrt(DH) * log2(e)

  dim3 tb(32, 8);
  transpose_cast_multi_kernel<<<6912, tb, 0, stream>>>(
      Wq, Wk, Wv, Wo, W1, W2, WqT, WkT, WvT, WoT, W1T, W2T);
  bias_cat_kernel<<<9, 256, 0, stream>>>(bq, bk, bv, bias_cat);

  layernorm_kernel<<<(B_*S_)/4, 256, 0, stream>>>(x, ln1g, ln1b, h);

  // fused QKV: one GEMM, N = 2304 (nN = 18), linear output [8192][2304]
  gemm_kernel<EPI_QKV><<<dim3(64*18), 256, 0, stream>>>(
      h, D_, WqT, D_, bias_cat, nullptr, nullptr, qkv, LDQ, qscale, 18);

  attn_kernel<<<dim3(768), 256, 0, stream>>>(qkv, ob);

  gemm_kernel<EPI_OPROJ><<<dim3(64*6), 256, 0, stream>>>(
      ob, D_, WoT, D_, bo, x, out, nullptr, D_, 1.0f, 6);

  layernorm_kernel<<<(B_*S_)/4, 256, 0, stream>>>(out, ln2g, ln2b, h2);

  gemm_kernel<EPI_GELU><<<dim3(64*24), 256, 0, stream>>>(
      h2, D_, W1T, D_, b1, nullptr, nullptr, ffb, FF_, 1.0f, 24);

  gemm_kernel<EPI_FINAL><<<dim3(64*6), 256, 0, stream>>>(
      ffb, FF_, W2T, FF_, b2, out, out, nullptr, D_, 1.0f, 6);
}

// Round 12
// 262.198 us; speedup vs baseline: 2.2036x; 2.2036x over previous
//
#include <hip/hip_runtime.h>
#include <math.h>

#define B_ 4
#define S_ 2048
#define D_ 768
#define H_ 12
#define DH_ 64
#define FF_ 3072
#define LDQ (3*D_)

using short8  = __attribute__((ext_vector_type(8))) short;
using f32x4   = __attribute__((ext_vector_type(4))) float;
using f32x16  = __attribute__((ext_vector_type(16))) float;
using float4v = __attribute__((ext_vector_type(4))) float;
using ushort4v= __attribute__((ext_vector_type(4))) unsigned short;

__device__ __forceinline__ unsigned short f2bf(float f) {
  unsigned u = __builtin_bit_cast(unsigned, f);
  u += 0x7FFFu + ((u >> 16) & 1u);   // round-to-nearest-even
  return (unsigned short)(u >> 16);
}

__device__ __forceinline__ unsigned cvt_pk_bf16(float a, float b) {
  unsigned r;
  asm("v_cvt_pk_bf16_f32 %0, %1, %2" : "=v"(r) : "v"(a), "v"(b));
  return r;   // lo = bf16(a), hi = bf16(b)
}

// tanh-form GELU: 0.5x(1+tanh(0.79788456(x+0.044715x^3))), max abs err ~3e-4.
__device__ __forceinline__ float gelu_tanh(float x) {
  float x2 = x * x;
  float y  = x * fmaf(0.0356774081f, x2, 0.7978845608f);
  float e  = exp2f(y * 2.885390082f);     // e^(2y)
  float t  = 1.0f - 2.0f / (e + 1.0f);
  float hx = 0.5f * x;
  return fmaf(hx, t, hx);
}

__device__ __forceinline__ void gload16(const void* g, void* l) {
  __builtin_amdgcn_global_load_lds(
      (const __attribute__((address_space(1))) unsigned*)g,
      (__attribute__((address_space(3))) unsigned*)l, 16, 0, 0);
}

// ---------------- fused weight transpose + cast (all 6 weights, one launch) ----------------
// in [K][N] f32 -> out [N][K] bf16
__global__ __launch_bounds__(256) void transpose_cast_multi_kernel(
    const float* __restrict__ Wq, const float* __restrict__ Wk,
    const float* __restrict__ Wv, const float* __restrict__ Wo,
    const float* __restrict__ W1, const float* __restrict__ W2,
    unsigned short* __restrict__ WqT, unsigned short* __restrict__ WkT,
    unsigned short* __restrict__ WvT, unsigned short* __restrict__ WoT,
    unsigned short* __restrict__ W1T, unsigned short* __restrict__ W2T) {
  __shared__ float tile[32][33];
  int bid = blockIdx.x;
  const float* in; unsigned short* out; int K, N, t;
  if (bid < 2304) {                 // Wq/Wk/Wv/Wo: 576 tiles each, 768x768
    int seg = bid / 576; t = bid % 576; K = D_; N = D_;
    in  = seg == 0 ? Wq  : seg == 1 ? Wk  : seg == 2 ? Wv  : Wo;
    out = seg == 0 ? WqT : seg == 1 ? WkT : seg == 2 ? WvT : WoT;
  } else if (bid < 4608) {          // W1: 768x3072
    t = bid - 2304; K = D_; N = FF_; in = W1; out = W1T;
  } else {                          // W2: 3072x768
    t = bid - 4608; K = FF_; N = D_; in = W2; out = W2T;
  }
  int ntk = K / 32;
  int k0 = (t % ntk) * 32, n0 = (t / ntk) * 32;
  int tx = threadIdx.x, ty = threadIdx.y;
#pragma unroll
  for (int i = 0; i < 4; i++)
    tile[ty + 8*i][tx] = in[(size_t)(k0 + ty + 8*i) * N + n0 + tx];
  __syncthreads();
#pragma unroll
  for (int i = 0; i < 4; i++)
    out[(size_t)(n0 + ty + 8*i) * K + k0 + tx] = f2bf(tile[tx][ty + 8*i]);
}

// ---------------- bias concat: [bq | bk | bv] -> 2304 floats ----------------
__global__ void bias_cat_kernel(const float* __restrict__ bq, const float* __restrict__ bk,
                                const float* __restrict__ bv, float* __restrict__ dst) {
  int i = blockIdx.x * 256 + threadIdx.x;
  if (i >= 3 * D_) return;
  float v;
  if (i < D_)            v = bq[i];
  else if (i < 2 * D_)   v = bk[i - D_];
  else                   v = bv[i - 2 * D_];
  dst[i] = v;
}

// ---------------- LayerNorm: fp32 in -> bf16 out, one wave per row of 768 ----------------
__global__ __launch_bounds__(256) void layernorm_kernel(
    const float* __restrict__ x, const float* __restrict__ g,
    const float* __restrict__ b, unsigned short* __restrict__ out) {
  int wave = threadIdx.x >> 6, lane = threadIdx.x & 63;
  int row = blockIdx.x * 4 + wave;
  const float* xr = x + (size_t)row * D_;
  float4v v[3];
  float sum = 0.f, sq = 0.f;
#pragma unroll
  for (int i = 0; i < 3; i++) {
    v[i] = reinterpret_cast<const float4v*>(xr)[lane + 64*i];
#pragma unroll
    for (int j = 0; j < 4; j++) { sum += v[i][j]; sq += v[i][j]*v[i][j]; }
  }
#pragma unroll
  for (int d = 1; d < 64; d <<= 1) { sum += __shfl_xor(sum, d); sq += __shfl_xor(sq, d); }
  float mu   = sum * (1.0f / D_);
  float var  = sq  * (1.0f / D_) - mu * mu;
  float rstd = rsqrtf(var + 1e-5f);
  unsigned short* orow = out + (size_t)row * D_;
#pragma unroll
  for (int i = 0; i < 3; i++) {
    int idx = (lane + 64*i) * 4;
    ushort4v o;
#pragma unroll
    for (int j = 0; j < 4; j++)
      o[j] = f2bf((v[i][j] - mu) * rstd * g[idx + j] + b[idx + j]);
    *reinterpret_cast<ushort4v*>(orow + idx) = o;
  }
}

// ---------------- bf16 MFMA GEMM v3 (round-10 structure, m-fastest XCD order) --------------
// 128x128 tile, BK=32, 4 waves. Unified A|B LDS row (128B, 8x16B slots, ^(row&7)
// swizzle -> measured-zero conflicts). 3-slot ring, counted vmcnt(4), one raw
// s_barrier per chunk; loads never drain to 0 mid-loop (depth-2: covers latency).
// XCD block order: m iterates FASTEST -> per-XCD working set = all 8 A-panels
// (1.5MB) + ~12 B-panels (2.3MB) < 4MB L2 (n-fastest spanned full B = thrash).
#define EPI_QKV   0
#define EPI_OPROJ 1
#define EPI_GELU  2
#define EPI_FINAL 3

template<int EPI>
__global__ __launch_bounds__(256) void gemm_kernel(
    const unsigned short* __restrict__ A, int lda,
    const unsigned short* __restrict__ BT, int K,
    const float* __restrict__ bias,
    const float* __restrict__ resid,
    float* __restrict__ outf,
    unsigned short* __restrict__ outh,
    int ldo, float ascale, int nN) {
  __shared__ __attribute__((aligned(16))) unsigned short Ls[3][128*64];
  int tid = threadIdx.x;
  int wave = tid >> 6, lane = tid & 63;
  int lrow = lane & 15, lk = lane >> 4;      // lk = k-slot 0..3 (8 elems each)
  int bid = blockIdx.x;
  int xcd = bid & 7, j = bid >> 3;
  int nM8 = gridDim.x / (8 * nN);            // = 8 (64 M-panels / 8 XCDs)
  int m0 = (xcd * nM8 + (j % nM8)) * 128;    // m fastest within XCD
  int n0 = (j / nM8) * 128;
  int wm = (wave >> 1) * 64, wn = (wave & 1) * 64;

  // Unified staging: LDS row r = [A[m0+r] slots 0..3 | B[n0+r] slots 4..7],
  // slot s8 holds content m = s8 ^ (r&7). Source pre-swizzled per-lane (rule #21).
  auto STAGE = [&](int buf, int k0) {
#pragma unroll
    for (int i = 0; i < 4; i++) {
      int ch = i * 256 + tid;
      int row = ch >> 3, s8 = ch & 7;
      int m = s8 ^ (row & 7);
      const unsigned short* src = (m < 4)
        ? A  + (size_t)(m0 + row) * lda + k0 + m * 8
        : BT + (size_t)(n0 + row) * K   + k0 + (m - 4) * 8;
      gload16(src, &Ls[buf][(i*256 + wave*64) * 8]);
    }
  };

  f32x4 acc[4][4] = {};
  int nt = K / 32;
  STAGE(0, 0);
  STAGE(1, 32);
  for (int t = 0; t < nt; t++) {
    // counted wait: stages t+1 (and t+2 after issue) stay in flight
    if (t + 1 < nt) { asm volatile("s_waitcnt vmcnt(4)" ::: "memory"); }
    else            { asm volatile("s_waitcnt vmcnt(0)" ::: "memory"); }
    __builtin_amdgcn_s_barrier();
    const unsigned short* Lc = Ls[t % 3];
    short8 af[4], bf[4];
#pragma unroll
    for (int mi = 0; mi < 4; mi++) {
      int row = wm + mi*16 + lrow;
      af[mi] = *reinterpret_cast<const short8*>(&Lc[row*64 + ((lk ^ (row & 7)) * 8)]);
    }
#pragma unroll
    for (int ni = 0; ni < 4; ni++) {
      int row = wn + ni*16 + lrow;
      bf[ni] = *reinterpret_cast<const short8*>(&Lc[row*64 + (((4 + lk) ^ (row & 7)) * 8)]);
    }
    if (t + 2 < nt) STAGE((t + 2) % 3, (t + 2) * 32);
    __builtin_amdgcn_s_setprio(1);
#pragma unroll
    for (int mi = 0; mi < 4; mi++)
#pragma unroll
      for (int ni = 0; ni < 4; ni++)
        acc[mi][ni] = __builtin_amdgcn_mfma_f32_16x16x32_bf16(af[mi], bf[ni], acc[mi][ni], 0, 0, 0);
    __builtin_amdgcn_s_setprio(0);
  }
#pragma unroll
  for (int mi = 0; mi < 4; mi++) {
#pragma unroll
    for (int ni = 0; ni < 4; ni++) {
#pragma unroll
      for (int r = 0; r < 4; r++) {
        int gm = m0 + wm + mi*16 + (lane >> 4)*4 + r;
        int gn = n0 + wn + ni*16 + lrow;
        float v = acc[mi][ni][r] + bias[gn];
        if constexpr (EPI == EPI_QKV) {
          if (gn < D_) v *= ascale;   // Q pre-scale: 1/sqrt(DH)*log2(e)
          float nb = __shfl_xor(v, 1);
          if (!(lane & 1))
            *reinterpret_cast<unsigned*>(&outh[(size_t)gm * ldo + gn]) = cvt_pk_bf16(v, nb);
        } else if constexpr (EPI == EPI_OPROJ) {
          size_t idx = (size_t)gm * ldo + gn;
          outf[idx] = v + resid[idx];
        } else if constexpr (EPI == EPI_GELU) {
          float gv = gelu_tanh(v);
          float nb = __shfl_xor(gv, 1);
          if (!(lane & 1))
            *reinterpret_cast<unsigned*>(&outh[(size_t)gm * ldo + gn]) = cvt_pk_bf16(gv, nb);
        } else {  // EPI_FINAL
          size_t idx = (size_t)gm * ldo + gn;
          outf[idx] = v + resid[idx];
        }
      }
    }
  }
}

// ---------------- causal flash attention v7 (unchanged from round 8) ----------------
__global__ __launch_bounds__(256, 3) void attn_kernel(
    const unsigned short* __restrict__ qkv,
    unsigned short* __restrict__ o) {
  __shared__ __attribute__((aligned(16))) unsigned short Ks[2][64*64];  // [key][dh] swizzled
  __shared__ __attribute__((aligned(16))) unsigned short VT[2][64*64];  // [dh][key] swizzled
  int tid = threadIdx.x;
  int wave = tid >> 6, lane = tid & 63;
  int ql = lane & 31, hi = lane >> 5;
  int bid = blockIdx.x;
  int xcd = bid & 7, r = bid >> 3;           // r in [0,96)
  int bh = xcd * 6 + (r % 6);                // 0..47, fixed per XCD
  int qtile = 15 - (r / 6);                  // heavy (15) first
  int bb = bh / H_, hh = bh % H_;
  const unsigned short* qb = qkv + (size_t)bb * S_ * LDQ + hh * DH_;
  const unsigned short* kb = qb + D_;
  const unsigned short* vb = qb + 2 * D_;

  int sr = tid >> 2;                 // K row 0..63
  int sc16 = (tid & 3) * 16;         // K col (elems)
  int kp = tid & 31, dh0 = (tid >> 5) * 8;
  uint4 krA, krB, vrA, vrB;

  auto LOADR = [&](int kb0) {
    const unsigned short* ksrc = kb + (size_t)(kb0 + sr) * LDQ + sc16;
    krA = *reinterpret_cast<const uint4*>(ksrc);
    krB = *reinterpret_cast<const uint4*>(ksrc + 8);
    const unsigned short* vsrc = vb + (size_t)(kb0 + 2*kp) * LDQ + dh0;
    vrA = *reinterpret_cast<const uint4*>(vsrc);
    vrB = *reinterpret_cast<const uint4*>(vsrc + LDQ);
  };
  auto WRITE = [&](int buf) {
    int sw = (sr & 7) << 4;
    int cb = sc16 * 2;
    *reinterpret_cast<uint4*>(&Ks[buf][(sr*128 + (cb ^ sw)) >> 1]) = krA;
    *reinterpret_cast<uint4*>(&Ks[buf][(sr*128 + ((cb + 16) ^ sw)) >> 1]) = krB;
    union { uint4 u4; unsigned short s[8]; } a, b;
    a.u4 = vrA; b.u4 = vrB;
#pragma unroll
    for (int j2 = 0; j2 < 8; j2++) {
      int row = dh0 + j2, sw2 = (row & 7) << 4;
      *reinterpret_cast<unsigned*>(&VT[buf][(row*128 + ((4*kp) ^ sw2)) >> 1]) =
          (unsigned)a.s[j2] | ((unsigned)b.s[j2] << 16);
    }
  };

  int q0 = qtile * 128;
  int qw = q0 + wave * 32;
  int myq = qw + ql;

  short8 qf[4];
#pragma unroll
  for (int dblk = 0; dblk < 4; dblk++)
    qf[dblk] = *reinterpret_cast<const short8*>(qb + (size_t)myq * LDQ + dblk*16 + hi*8);

  f32x16 oaccT[2] = {};
  float mst = -1e30f, lst = 0.f;
  int nt = q0 / 64 + 2;   // always even

  auto TILE = [&](int kt, int cur) {
    int kb0 = kt * 64;
    bool has_next = (kt + 1 < nt);
    if (has_next) LOADR((kt + 1) * 64);   // early issue

    if (kb0 <= qw + 31) {
      f32x16 sc[2] = {};
      __builtin_amdgcn_s_setprio(1);
#pragma unroll
      for (int dblk = 0; dblk < 4; dblk++) {
#pragma unroll
        for (int blk = 0; blk < 2; blk++) {
          int row = blk*32 + ql;
          int sw = (row & 7) << 4;
          short8 kf = *reinterpret_cast<const short8*>(
              &Ks[cur][(row*128 + (((unsigned)(dblk*32 + hi*16)) ^ sw)) >> 1]);
          sc[blk] = __builtin_amdgcn_mfma_f32_32x32x16_bf16(kf, qf[dblk], sc[blk], 0, 0, 0);
        }
      }
      __builtin_amdgcn_s_setprio(0);
      bool full = (kb0 + 63 <= qw);
      if (!full) {
#pragma unroll
        for (int blk = 0; blk < 2; blk++)
#pragma unroll
          for (int r2 = 0; r2 < 16; r2++) {
            int key = kb0 + blk*32 + (r2 & 3) + 8*(r2 >> 2) + 4*hi;
            if (key > myq) sc[blk][r2] = -1e30f;
          }
      }
      float pm0 = -1e30f, pm1 = -1e30f, pm2 = -1e30f, pm3 = -1e30f;
#pragma unroll
      for (int blk = 0; blk < 2; blk++)
#pragma unroll
        for (int g = 0; g < 4; g++) {
          pm0 = fmaxf(pm0, sc[blk][4*g]);
          pm1 = fmaxf(pm1, sc[blk][4*g+1]);
          pm2 = fmaxf(pm2, sc[blk][4*g+2]);
          pm3 = fmaxf(pm3, sc[blk][4*g+3]);
        }
      float mx = fmaxf(fmaxf(pm0, pm1), fmaxf(pm2, pm3));
      mx = fmaxf(mx, __shfl_xor(mx, 32));
      if (!__all(mx <= mst + 8.0f)) {
        float mnew = fmaxf(mst, mx);
        float fac = exp2f(mst - mnew);
        lst *= fac;
#pragma unroll
        for (int db = 0; db < 2; db++)
#pragma unroll
          for (int r2 = 0; r2 < 16; r2++) oaccT[db][r2] *= fac;
        mst = mnew;
      }
      short8 pa[4];
      float rs = 0.f;
#pragma unroll
      for (int b = 0; b < 2; b++) {
#pragma unroll
        for (int so = 0; so < 2; so++) {
          float p0 = exp2f(sc[b][8*so + 0] - mst);
          float p1 = exp2f(sc[b][8*so + 1] - mst);
          float p2 = exp2f(sc[b][8*so + 2] - mst);
          float p3 = exp2f(sc[b][8*so + 3] - mst);
          float p4 = exp2f(sc[b][8*so + 4] - mst);
          float p5 = exp2f(sc[b][8*so + 5] - mst);
          float p6 = exp2f(sc[b][8*so + 6] - mst);
          float p7 = exp2f(sc[b][8*so + 7] - mst);
          rs += ((p0 + p1) + (p2 + p3)) + ((p4 + p5) + (p6 + p7));
          unsigned W0 = cvt_pk_bf16(p0, p1);
          unsigned W1 = cvt_pk_bf16(p2, p3);
          unsigned W2 = cvt_pk_bf16(p4, p5);
          unsigned W3 = cvt_pk_bf16(p6, p7);
          asm volatile("v_permlane32_swap_b32 %0, %1" : "+v"(W0), "+v"(W2));
          asm volatile("v_permlane32_swap_b32 %0, %1" : "+v"(W1), "+v"(W3));
          union { uint4 u; short8 s; } cvtu;
          cvtu.u.x = W0; cvtu.u.y = W1; cvtu.u.z = W2; cvtu.u.w = W3;
          pa[2*b + so] = cvtu.s;
        }
      }
      rs += __shfl_xor(rs, 32);
      lst += rs;
      __builtin_amdgcn_s_setprio(1);
#pragma unroll
      for (int ks = 0; ks < 4; ks++) {
        int cb = ks*32 + hi*16;
#pragma unroll
        for (int db = 0; db < 2; db++) {
          int row = db*32 + ql;
          int sw = (row & 7) << 4;
          short8 vf = *reinterpret_cast<const short8*>(&VT[cur][(row*128 + (cb ^ sw)) >> 1]);
          oaccT[db] = __builtin_amdgcn_mfma_f32_32x32x16_bf16(vf, pa[ks], oaccT[db], 0, 0, 0);
        }
      }
      __builtin_amdgcn_s_setprio(0);
    }

    if (has_next) WRITE(cur ^ 1);
    __syncthreads();
  };

  LOADR(0);
  WRITE(0);
  __syncthreads();
  for (int kt = 0; kt < nt; kt += 2) {
    TILE(kt, 0);
    TILE(kt + 1, 1);
  }

  float inv = 1.0f / lst;
  unsigned short* ob = o + ((size_t)(bb * S_ + myq)) * D_ + hh * DH_;
#pragma unroll
  for (int db = 0; db < 2; db++)
#pragma unroll
    for (int g = 0; g < 8; g++) {
      int r2 = 2 * g;
      int dh = db*32 + (r2 & 3) + 8*(r2 >> 2) + 4*hi;
      unsigned pk = cvt_pk_bf16(oaccT[db][r2] * inv, oaccT[db][r2+1] * inv);
      *reinterpret_cast<unsigned*>(ob + dh) = pk;
    }
}

extern "C" void kernel_launch(void* const* d_in, const int* in_sizes, int n_in,
                              void* d_out, int out_size, void* d_ws, size_t ws_size,
                              hipStream_t stream) {
  (void)in_sizes; (void)n_in; (void)out_size; (void)ws_size;
  const float* x    = (const float*)d_in[0];
  const float* ln1g = (const float*)d_in[1];
  const float* ln1b = (const float*)d_in[2];
  const float* Wq   = (const float*)d_in[3];
  const float* bq   = (const float*)d_in[4];
  const float* Wk   = (const float*)d_in[5];
  const float* bk   = (const float*)d_in[6];
  const float* Wv   = (const float*)d_in[7];
  const float* bv   = (const float*)d_in[8];
  const float* Wo   = (const float*)d_in[9];
  const float* bo   = (const float*)d_in[10];
  const float* ln2g = (const float*)d_in[11];
  const float* ln2b = (const float*)d_in[12];
  const float* W1   = (const float*)d_in[13];
  const float* b1   = (const float*)d_in[14];
  const float* W2   = (const float*)d_in[15];
  const float* b2   = (const float*)d_in[16];
  float* out = (float*)d_out;

  char* ws = (char*)d_ws;
  size_t off = 0;
  auto alloc = [&](size_t bytes) {
    char* p = ws + off;
    off += (bytes + 255) & ~(size_t)255;
    return p;
  };
  unsigned short* WqT = (unsigned short*)alloc((size_t)D_*D_*2);
  unsigned short* WkT = (unsigned short*)alloc((size_t)D_*D_*2);
  unsigned short* WvT = (unsigned short*)alloc((size_t)D_*D_*2);
  unsigned short* WoT = (unsigned short*)alloc((size_t)D_*D_*2);
  unsigned short* W1T = (unsigned short*)alloc((size_t)D_*FF_*2);
  unsigned short* W2T = (unsigned short*)alloc((size_t)FF_*D_*2);
  unsigned short* h   = (unsigned short*)alloc((size_t)B_*S_*D_*2);
  unsigned short* qkv = (unsigned short*)alloc((size_t)B_*S_*LDQ*2);  // [8192][2304]
  unsigned short* ob  = (unsigned short*)alloc((size_t)B_*S_*D_*2);   // [8192][768]
  float* bias_cat     = (float*)alloc((size_t)3*D_*4);
  unsigned short* ffb = qkv;  // reuse qkv+ob span (50.3MB = B*S*FF*2)
  unsigned short* h2  = h;    // reuse h

  const float qscale = 0.125f * 1.4426950408889634f;  // 1/sqrt(DH) * log2(e)

  dim3 tb(32, 8);
  transpose_cast_multi_kernel<<<6912, tb, 0, stream>>>(
      Wq, Wk, Wv, Wo, W1, W2, WqT, WkT, WvT, WoT, W1T, W2T);
  bias_cat_kernel<<<9, 256, 0, stream>>>(bq, bk, bv, bias_cat);

  layernorm_kernel<<<(B_*S_)/4, 256, 0, stream>>>(x, ln1g, ln1b, h);

  // fused QKV: one GEMM, N = 2304 (nN = 18), linear output [8192][2304]
  gemm_kernel<EPI_QKV><<<dim3(64*18), 256, 0, stream>>>(
      h, D_, WqT, D_, bias_cat, nullptr, nullptr, qkv, LDQ, qscale, 18);

  attn_kernel<<<dim3(768), 256, 0, stream>>>(qkv, ob);

  gemm_kernel<EPI_OPROJ><<<dim3(64*6), 256, 0, stream>>>(
      ob, D_, WoT, D_, bo, x, out, nullptr, D_, 1.0f, 6);

  layernorm_kernel<<<(B_*S_)/4, 256, 0, stream>>>(out, ln2g, ln2b, h2);

  gemm_kernel<EPI_GELU><<<dim3(64*24), 256, 0, stream>>>(
      h2, D_, W1T, D_, b1, nullptr, nullptr, ffb, FF_, 1.0f, 24);

  gemm_kernel<EPI_FINAL><<<dim3(64*6), 256, 0, stream>>>(
      ffb, FF_, W2T, FF_, b2, out, out, nullptr, D_, 1.0f, 6);
}